// Round 1
// baseline (349.709 us; speedup 1.0000x reference)
//
#include <hip/hip_runtime.h>
#include <math.h>

// SSIM loss, fused single-pass kernel.
// 96 planes of 512x512. 64x64 output tile per block, 256 threads.
// Each thread: 2 adjacent columns x 8 rows = 16 output pixels.
// Horizontal 11-tap conv from LDS (12 shared taps for the 2 columns),
// vertical 11-tap conv via register scatter-accumulate.

#define IMG 512
#define TILE 64
#define HALO 5
#define LROWS 74            // TILE + 2*HALO
#define LCOLS 74
#define LSTRIDE 76          // float2 stride; even -> 16B-aligned b128 tap reads
#define RPT 8               // output rows per thread
#define NPIX 25165824.0     // 32*3*512*512

__global__ __launch_bounds__(256) void ssim_main(
    const float* __restrict__ clean,
    const float* __restrict__ adv,
    double* __restrict__ accum)
{
    __shared__ __align__(16) float2 tile[LROWS * LSTRIDE];
    __shared__ float wpart[4];

    const int tid = threadIdx.x;
    const int b = blockIdx.x;
    const int plane = b >> 6;         // 64 tiles per plane
    const int t6 = b & 63;
    const int tile_x = (t6 & 7) * TILE;
    const int tile_y = (t6 >> 3) * TILE;

    const float* __restrict__ cp = clean + (size_t)plane * (IMG * IMG);
    const float* __restrict__ ap = adv   + (size_t)plane * (IMG * IMG);

    // Gaussian weights (match reference: fp32 exp, normalized)
    float wt[11];
    {
        float s = 0.f;
        #pragma unroll
        for (int i = 0; i < 11; ++i) {
            float d = (float)(i - 5);
            wt[i] = expf(-(d * d) / 4.5f);
            s += wt[i];
        }
        float inv = 1.f / s;
        #pragma unroll
        for (int i = 0; i < 11; ++i) wt[i] *= inv;
    }

    // ---- Stage haloed tile (zero-padded at plane edges) ----
    for (int idx = tid; idx < LROWS * LCOLS; idx += 256) {
        int r = idx / LCOLS;
        int c = idx - r * LCOLS;
        int gr = tile_y + r - HALO;
        int gc = tile_x + c - HALO;
        float x = 0.f, y = 0.f;
        if (gr >= 0 && gr < IMG && gc >= 0 && gc < IMG) {
            int gi = gr * IMG + gc;
            x = cp[gi];
            y = ap[gi];
        }
        tile[r * LSTRIDE + c] = make_float2(x, y);
    }
    __syncthreads();

    // ---- Compute ----
    const int cpair = tid & 31;       // column pair: output cols 2*cpair, 2*cpair+1
    const int trow = tid >> 5;        // 0..7
    const int r0 = trow * RPT;        // output rows r0..r0+7 (tile coords)

    // acc[o][f], f: 0=mu1 1=mu2 2=Exx 3=Eyy 4=Exy ; .x = col0, .y = col1
    float2 acc[RPT][5];
    #pragma unroll
    for (int o = 0; o < RPT; ++o)
        #pragma unroll
        for (int f = 0; f < 5; ++f)
            acc[o][f] = make_float2(0.f, 0.f);

    // Input LDS rows needed: r0 .. r0+17 (output row r uses LDS rows r..r+10)
    #pragma unroll
    for (int j = 0; j < RPT + 10; ++j) {
        const float2* __restrict__ rp = &tile[(r0 + j) * LSTRIDE + 2 * cpair];

        // 12 taps cover both columns' 11-tap windows; 6x ds_read_b128
        float2 tp[12];
        #pragma unroll
        for (int k = 0; k < 12; ++k) tp[k] = rp[k];

        // horizontal conv: h*.x = col0 (taps 0..10), h*.y = col1 (taps 1..11)
        float2 hx  = make_float2(0.f, 0.f);
        float2 hy  = make_float2(0.f, 0.f);
        float2 hxx = make_float2(0.f, 0.f);
        float2 hyy = make_float2(0.f, 0.f);
        float2 hxy = make_float2(0.f, 0.f);
        #pragma unroll
        for (int k = 0; k < 12; ++k) {
            float x = tp[k].x, y = tp[k].y;
            float xx = x * x, yy = y * y, xy = x * y;
            if (k < 11) {
                float w = wt[k];
                hx.x  += w * x;  hy.x  += w * y;
                hxx.x += w * xx; hyy.x += w * yy; hxy.x += w * xy;
            }
            if (k > 0) {
                float w = wt[k - 1];
                hx.y  += w * x;  hy.y  += w * y;
                hxx.y += w * xx; hyy.y += w * yy; hxy.y += w * xy;
            }
        }

        // vertical scatter into row accumulators (static after unroll)
        #pragma unroll
        for (int o = 0; o < RPT; ++o) {
            int kv = j - o;
            if (kv >= 0 && kv <= 10) {
                float w = wt[kv];
                acc[o][0].x += w * hx.x;  acc[o][0].y += w * hx.y;
                acc[o][1].x += w * hy.x;  acc[o][1].y += w * hy.y;
                acc[o][2].x += w * hxx.x; acc[o][2].y += w * hxx.y;
                acc[o][3].x += w * hyy.x; acc[o][3].y += w * hyy.y;
                acc[o][4].x += w * hxy.x; acc[o][4].y += w * hxy.y;
            }
        }
    }

    // ---- SSIM formula + local sum ----
    const float C1 = 1e-4f;   // 0.01^2
    const float C2 = 9e-4f;   // 0.03^2
    float lsum = 0.f;
    #pragma unroll
    for (int o = 0; o < RPT; ++o) {
        #pragma unroll
        for (int s = 0; s < 2; ++s) {
            float mu1 = s ? acc[o][0].y : acc[o][0].x;
            float mu2 = s ? acc[o][1].y : acc[o][1].x;
            float exx = s ? acc[o][2].y : acc[o][2].x;
            float eyy = s ? acc[o][3].y : acc[o][3].x;
            float exy = s ? acc[o][4].y : acc[o][4].x;
            float mu1s = mu1 * mu1;
            float mu2s = mu2 * mu2;
            float mu12 = mu1 * mu2;
            float s1 = exx - mu1s;
            float s2 = eyy - mu2s;
            float s12 = exy - mu12;
            float num = (2.f * mu12 + C1) * (2.f * s12 + C2);
            float den = (mu1s + mu2s + C1) * (s1 + s2 + C2);
            lsum += num * __builtin_amdgcn_rcpf(den);
        }
    }

    // ---- Reduce: wave shuffle -> LDS -> one atomic per block ----
    #pragma unroll
    for (int off = 32; off > 0; off >>= 1)
        lsum += __shfl_down(lsum, off);
    const int lane = tid & 63;
    const int wave = tid >> 6;
    if (lane == 0) wpart[wave] = lsum;
    __syncthreads();
    if (tid == 0) {
        float bs = wpart[0] + wpart[1] + wpart[2] + wpart[3];
        atomicAdd(accum, (double)bs);
    }
}

__global__ void ssim_finalize(const double* __restrict__ accum,
                              float* __restrict__ out)
{
    if (threadIdx.x == 0) {
        out[0] = 1.f - (float)(accum[0] / NPIX);
    }
}

extern "C" void kernel_launch(void* const* d_in, const int* in_sizes, int n_in,
                              void* d_out, int out_size, void* d_ws, size_t ws_size,
                              hipStream_t stream)
{
    const float* clean = (const float*)d_in[0];
    const float* adv   = (const float*)d_in[1];
    float* out = (float*)d_out;
    double* accum = (double*)d_ws;

    hipMemsetAsync(accum, 0, sizeof(double), stream);

    const int nblocks = 96 * 64;   // 96 planes * (8x8 tiles)
    ssim_main<<<nblocks, 256, 0, stream>>>(clean, adv, accum);
    ssim_finalize<<<1, 64, 0, stream>>>(accum, out);
}

// Round 2
// 330.110 us; speedup vs baseline: 1.0594x; 1.0594x over previous
//
#include <hip/hip_runtime.h>

// SSIM loss, fused single-pass kernel. 96 planes of 512x512.
// 64x64 output tile per block, 256 threads; each thread: 2 adjacent
// columns x 8 rows = 16 output pixels. Separable 11-tap Gaussian:
// horizontal conv from LDS (12 shared taps cover both columns),
// vertical conv via fully-unrolled register scatter-accumulate.
//
// R2 changes vs R1: compile-time weight literals (expf removed) so the
// scatter guards constant-fold and SROA keeps all 80 accumulators in
// VGPRs (R1 had VGPR_Count=68 -> accumulators in scratch, 225us).
// ext_vector float2 ops to enable v_pk_fma_f32. __launch_bounds__(256,3)
// aligns the VGPR budget (170) with the LDS-limited 3 blocks/CU.

typedef float v2f __attribute__((ext_vector_type(2)));

#define IMG 512
#define TILE 64
#define HALO 5
#define LROWS 74            // TILE + 2*HALO
#define LCOLS 74
#define LSTRIDE 76          // v2f stride; even -> 16B-aligned tap reads
#define RPT 8               // output rows per thread
#define NPIX 25165824.0     // 32*3*512*512

// Gaussian(sigma=1.5, 11 taps), normalized; fp32-rounded reference values.
__device__ __constant__ const float WT_[1] = {0.f}; // (unused; keep literals)
#define W0 0.00102838f
#define W1 0.00759876f
#define W2 0.03600077f
#define W3 0.10936068f
#define W4 0.21300552f
#define W5 0.26601173f
__device__ constexpr float WT[11] = {W0, W1, W2, W3, W4, W5, W4, W3, W2, W1, W0};

__global__ __launch_bounds__(256, 3) void ssim_main(
    const float* __restrict__ clean,
    const float* __restrict__ adv,
    double* __restrict__ accum)
{
    __shared__ __align__(16) v2f tile[LROWS * LSTRIDE];
    __shared__ float wpart[4];

    const int tid = threadIdx.x;
    const int b = blockIdx.x;
    const int plane = b >> 6;         // 64 tiles per plane
    const int t6 = b & 63;
    const int tile_x = (t6 & 7) * TILE;
    const int tile_y = (t6 >> 3) * TILE;

    const float* __restrict__ cp = clean + (size_t)plane * (IMG * IMG);
    const float* __restrict__ ap = adv   + (size_t)plane * (IMG * IMG);

    // ---- Stage haloed tile (zero-padded at plane edges) ----
    for (int idx = tid; idx < LROWS * LCOLS; idx += 256) {
        int r = idx / LCOLS;
        int c = idx - r * LCOLS;
        int gr = tile_y + r - HALO;
        int gc = tile_x + c - HALO;
        v2f v = {0.f, 0.f};
        if (gr >= 0 && gr < IMG && gc >= 0 && gc < IMG) {
            int gi = gr * IMG + gc;
            v.x = cp[gi];
            v.y = ap[gi];
        }
        tile[r * LSTRIDE + c] = v;
    }
    __syncthreads();

    // ---- Compute ----
    const int cpair = tid & 31;       // output cols 2*cpair, 2*cpair+1
    const int trow = tid >> 5;        // 0..7
    const int r0 = trow * RPT;        // output rows r0..r0+7 (tile coords)

    // Accumulators: per output row o, per column {0,1}:
    //   amu (mu1,mu2 packed), app (E[x^2],E[y^2] packed), axy (E[xy])
    v2f amu0[RPT], amu1[RPT], app0[RPT], app1[RPT];
    float axy0[RPT], axy1[RPT];
    #pragma unroll
    for (int o = 0; o < RPT; ++o) {
        amu0[o] = (v2f){0.f, 0.f}; amu1[o] = (v2f){0.f, 0.f};
        app0[o] = (v2f){0.f, 0.f}; app1[o] = (v2f){0.f, 0.f};
        axy0[o] = 0.f; axy1[o] = 0.f;
    }

    // Input LDS rows r0 .. r0+17 (output row r uses LDS rows r..r+10)
    #pragma unroll
    for (int j = 0; j < RPT + 10; ++j) {
        const v2f* __restrict__ rp = &tile[(r0 + j) * LSTRIDE + 2 * cpair];

        // 12 taps cover both columns' 11-tap windows (6x ds_read_b128)
        v2f tp[12];
        #pragma unroll
        for (int k = 0; k < 12; ++k) tp[k] = rp[k];

        // Horizontal conv. col0 uses taps 0..10, col1 uses taps 1..11.
        v2f hmu0 = {0.f, 0.f}, hmu1 = {0.f, 0.f};
        v2f hpp0 = {0.f, 0.f}, hpp1 = {0.f, 0.f};
        float hxy0 = 0.f, hxy1 = 0.f;
        #pragma unroll
        for (int k = 0; k < 12; ++k) {
            v2f t = tp[k];
            v2f pp = t * t;           // (x^2, y^2)
            float xy = t.x * t.y;
            if (k < 11) {
                const float w = WT[k];
                hmu0 += w * t; hpp0 += w * pp; hxy0 += w * xy;
            }
            if (k > 0) {
                const float w = WT[k - 1];
                hmu1 += w * t; hpp1 += w * pp; hxy1 += w * xy;
            }
        }

        // Vertical scatter (all guards fold after unroll: kv compile-time)
        #pragma unroll
        for (int o = 0; o < RPT; ++o) {
            const int kv = j - o;
            if (kv >= 0 && kv < 11) {
                const float w = WT[kv];
                amu0[o] += w * hmu0; amu1[o] += w * hmu1;
                app0[o] += w * hpp0; app1[o] += w * hpp1;
                axy0[o] += w * hxy0; axy1[o] += w * hxy1;
            }
        }
    }

    // ---- SSIM formula + local sum ----
    const float C1 = 1e-4f;   // 0.01^2
    const float C2 = 9e-4f;   // 0.03^2
    float lsum = 0.f;
    #pragma unroll
    for (int o = 0; o < RPT; ++o) {
        #pragma unroll
        for (int s = 0; s < 2; ++s) {
            v2f amu = s ? amu1[o] : amu0[o];
            v2f app = s ? app1[o] : app0[o];
            float exy = s ? axy1[o] : axy0[o];
            float mu1 = amu.x, mu2 = amu.y;
            float mu1s = mu1 * mu1;
            float mu2s = mu2 * mu2;
            float mu12 = mu1 * mu2;
            float s1 = app.x - mu1s;
            float s2 = app.y - mu2s;
            float s12 = exy - mu12;
            float num = (2.f * mu12 + C1) * (2.f * s12 + C2);
            float den = (mu1s + mu2s + C1) * (s1 + s2 + C2);
            lsum += num * __builtin_amdgcn_rcpf(den);
        }
    }

    // ---- Reduce: wave shuffle -> LDS -> one atomic per block ----
    #pragma unroll
    for (int off = 32; off > 0; off >>= 1)
        lsum += __shfl_down(lsum, off);
    const int lane = tid & 63;
    const int wave = tid >> 6;
    if (lane == 0) wpart[wave] = lsum;
    __syncthreads();
    if (tid == 0) {
        float bs = wpart[0] + wpart[1] + wpart[2] + wpart[3];
        atomicAdd(accum, (double)bs);
    }
}

__global__ void ssim_finalize(const double* __restrict__ accum,
                              float* __restrict__ out)
{
    if (threadIdx.x == 0) {
        out[0] = 1.f - (float)(accum[0] / NPIX);
    }
}

extern "C" void kernel_launch(void* const* d_in, const int* in_sizes, int n_in,
                              void* d_out, int out_size, void* d_ws, size_t ws_size,
                              hipStream_t stream)
{
    const float* clean = (const float*)d_in[0];
    const float* adv   = (const float*)d_in[1];
    float* out = (float*)d_out;
    double* accum = (double*)d_ws;

    hipMemsetAsync(accum, 0, sizeof(double), stream);

    const int nblocks = 96 * 64;   // 96 planes * (8x8 tiles of 64x64)
    ssim_main<<<nblocks, 256, 0, stream>>>(clean, adv, accum);
    ssim_finalize<<<1, 64, 0, stream>>>(accum, out);
}